// Round 6
// baseline (401.250 us; speedup 1.0000x reference)
//
#include <hip/hip_runtime.h>
#include <math.h>
#include <stdint.h>

#define B_ 64
#define J_ 512
#define D_ 1024

typedef __attribute__((ext_vector_type(8))) short short8;
typedef __attribute__((ext_vector_type(4))) float f32x4;

#define GLOBAL_AS __attribute__((address_space(1)))
#define LDS_AS    __attribute__((address_space(3)))

__device__ __forceinline__ void async16(const void* g, void* l) {
    __builtin_amdgcn_global_load_lds((const GLOBAL_AS uint32_t*)g,
                                     (LDS_AS uint32_t*)l, 16, 0, 0);
}

// tanh(x) = 1 - 2/(1+e^{2x}); saturates correctly for |x| large.
__device__ __forceinline__ float fast_tanh(float x) {
    return 1.0f - 2.0f / (1.0f + __expf(2.0f * x));
}

// fp32 -> bf16 round-to-nearest-even
__device__ __forceinline__ uint32_t f2bf(float f) {
    uint32_t u = __builtin_bit_cast(uint32_t, f);
    u += 0x7fffu + ((u >> 16) & 1u);
    return u >> 16;
}
__device__ __forceinline__ uint32_t pack2(float lo, float hi) {
    return f2bf(lo) | (f2bf(hi) << 16);
}

// W1[k][n] fp32 -> W1t[n][k] bf16. 64x64 tiles, 256 blocks, vectorized both ways.
// Also zeroes the per-batch finalize counters (runs before gemm on the stream).
__global__ __launch_bounds__(256) void transpose_cast_w1(
    const float* __restrict__ W1, unsigned short* __restrict__ W1t,
    unsigned int* __restrict__ cnt)
{
    if (blockIdx.x == 0 && blockIdx.y == 0 && threadIdx.x < B_)
        cnt[threadIdx.x] = 0u;

    __shared__ float t[64][65];
    const int tx = threadIdx.x;
    const int k0 = blockIdx.y * 64;
    const int n0 = blockIdx.x * 64;

    // read 64x64 fp32: thread reads 4 float4 (rows kr+16j, cols c4..c4+3), coalesced
    const int kr = tx >> 4;            // 0..15
    const int c4 = (tx & 15) << 2;     // 0..60
    #pragma unroll
    for (int j = 0; j < 4; ++j) {
        const float4 v = *reinterpret_cast<const float4*>(
            &W1[(size_t)(k0 + kr + 16 * j) * D_ + n0 + c4]);
        t[kr + 16 * j][c4 + 0] = v.x;
        t[kr + 16 * j][c4 + 1] = v.y;
        t[kr + 16 * j][c4 + 2] = v.z;
        t[kr + 16 * j][c4 + 3] = v.w;
    }
    __syncthreads();

    // write: thread covers 2 n-rows x 8 consecutive k as one uint4 (16B), coalesced
    const int nl = tx >> 3;            // 0..31
    const int k8 = (tx & 7) << 3;      // 0..56
    #pragma unroll
    for (int s = 0; s < 2; ++s) {
        const int n = nl + 32 * s;
        uint4 o;
        o.x = pack2(t[k8 + 0][n], t[k8 + 1][n]);
        o.y = pack2(t[k8 + 2][n], t[k8 + 3][n]);
        o.z = pack2(t[k8 + 4][n], t[k8 + 5][n]);
        o.w = pack2(t[k8 + 6][n], t[k8 + 7][n]);
        *reinterpret_cast<uint4*>(&W1t[(size_t)(n0 + n) * D_ + k0 + k8]) = o;
    }
}

// Block tile: 64(M) x 256(N-chunk) x 4 sweeps, BK=64. 4 waves, wave tile 64x64.
// A-path software-pipelined: global fp32 loads for k0+64 issued during k0's MFMA
// burst (consumed next iter) -> VMEM latency hidden, barrier drains only LDS+async16.
// Last-finishing block per batch runs the finalize inline (counter in ws, zeroed
// by transpose kernel; threadfence release/acquire; no extra dispatch).
__global__ __launch_bounds__(256, 2) void gemm_score_kernel(
    const float* __restrict__ x, const unsigned short* __restrict__ W1t,
    const float* __restrict__ b1, const float* __restrict__ W2,
    const float* __restrict__ b2, const float* __restrict__ mask,
    const float* __restrict__ W3, const float* __restrict__ b3,
    float* __restrict__ out, float* __restrict__ val_ws,
    float* __restrict__ pooled_part, unsigned int* __restrict__ cnt)
{
    __shared__ __align__(16) unsigned short ldsA[64 * 64];    // [m][k], swizzled chunks
    __shared__ __align__(16) unsigned short ldsB[256 * 64];   // [n][k], swizzled chunks
    __shared__ float pv_part[4][64];   // reused as sred[256] in inline finalize
    __shared__ float vrow[64];
    __shared__ int lastflag;

    const int tid  = threadIdx.x;
    const int wave = tid >> 6;
    const int l    = tid & 63;
    const int l15  = l & 15;
    const int kgrp = l >> 4;
    const int l7   = l & 7;
    const int r0   = blockIdx.x * 64;   // rows of this block (within one batch)
    const int bb   = r0 >> 9;           // batch index

    // A staging: thread owns 2 rows x 8 fp32 per k-iter, packs bf16, swizzled write
    const int ar = tid >> 3;            // 0..31
    const int ac = tid & 7;             // logical k-chunk
    const float* gA0 = x + (size_t)(r0 + ar) * D_ + (ac << 3);
    const float* gA1 = gA0 + (size_t)32 * D_;
    uint4* dA0 = (uint4*)(ldsA + ar * 64 + ((ac ^ (ar & 7)) << 3));
    uint4* dA1 = (uint4*)(ldsA + (ar + 32) * 64 + ((ac ^ (ar & 7)) << 3));

    // B staging via global_load_lds (validated r2/r5): lds dest = wave base +
    // lane*16; global address carries the swizzle.
    const int brl  = l >> 3;
    const int blog = (l & 7) ^ brl;
    const unsigned short* gBbase = W1t + (size_t)(wave * 8 + brl) * D_ + (blog << 3);
    unsigned short* lBbase = ldsB + wave * 512;

    // fragment LDS offsets (ushort units), swizzle-consistent (validated r2/r5)
    int aoff[4][2], boff[4][2];
    #pragma unroll
    for (int mi = 0; mi < 4; ++mi)
        #pragma unroll
        for (int ks = 0; ks < 2; ++ks)
            aoff[mi][ks] = (mi * 16 + l15) * 64 + (((ks * 4 + kgrp) ^ l7) << 3);
    #pragma unroll
    for (int ni = 0; ni < 4; ++ni)
        #pragma unroll
        for (int ks = 0; ks < 2; ++ks) {
            const int row = wave * 64 + ni * 16 + l15;
            boff[ni][ks] = row * 64 + (((ks * 4 + kgrp) ^ l7) << 3);
        }

    float pv[4][4];
    #pragma unroll
    for (int mi = 0; mi < 4; ++mi)
        #pragma unroll
        for (int r = 0; r < 4; ++r) pv[mi][r] = 0.f;

    // initial A prefetch (k=0)
    float4 pa00 = *reinterpret_cast<const float4*>(gA0);
    float4 pa01 = *reinterpret_cast<const float4*>(gA0 + 4);
    float4 pa10 = *reinterpret_cast<const float4*>(gA1);
    float4 pa11 = *reinterpret_cast<const float4*>(gA1 + 4);

    for (int n0 = 0; n0 < 4; ++n0) {
        f32x4 acc[4][4];
        #pragma unroll
        for (int mi = 0; mi < 4; ++mi)
            #pragma unroll
            for (int ni = 0; ni < 4; ++ni)
                acc[mi][ni] = (f32x4){0.f, 0.f, 0.f, 0.f};

        const size_t nofs = (size_t)n0 * 256 * D_;
        for (int k0 = 0; k0 < D_; k0 += 64) {
            // stage A from prefetched regs (loaded one k-iter ago; vmcnt hidden)
            uint4 p0, p1;
            p0.x = pack2(pa00.x, pa00.y); p0.y = pack2(pa00.z, pa00.w);
            p0.z = pack2(pa01.x, pa01.y); p0.w = pack2(pa01.z, pa01.w);
            p1.x = pack2(pa10.x, pa10.y); p1.y = pack2(pa10.z, pa10.w);
            p1.z = pack2(pa11.x, pa11.y); p1.w = pack2(pa11.z, pa11.w);
            *dA0 = p0;
            *dA1 = p1;
            #pragma unroll
            for (int t = 0; t < 8; ++t)
                async16(gBbase + nofs + (size_t)t * 32 * D_ + k0,
                        lBbase + t * 2048);
            __syncthreads();

            // prefetch A for next k-iter (wraps to k=0 exactly when the next
            // sweep restarts at k0=0 — no waste, no branch)
            const int nk = (k0 + 64) & (D_ - 1);
            pa00 = *reinterpret_cast<const float4*>(gA0 + nk);
            pa01 = *reinterpret_cast<const float4*>(gA0 + nk + 4);
            pa10 = *reinterpret_cast<const float4*>(gA1 + nk);
            pa11 = *reinterpret_cast<const float4*>(gA1 + nk + 4);

            #pragma unroll
            for (int ks = 0; ks < 2; ++ks) {
                short8 af[4], bfr[4];
                #pragma unroll
                for (int mi = 0; mi < 4; ++mi)
                    af[mi] = *reinterpret_cast<const short8*>(ldsA + aoff[mi][ks]);
                #pragma unroll
                for (int ni = 0; ni < 4; ++ni)
                    bfr[ni] = *reinterpret_cast<const short8*>(ldsB + boff[ni][ks]);
                #pragma unroll
                for (int mi = 0; mi < 4; ++mi)
                    #pragma unroll
                    for (int ni = 0; ni < 4; ++ni)
                        acc[mi][ni] = __builtin_amdgcn_mfma_f32_16x16x32_bf16(
                            af[mi], bfr[ni], acc[mi][ni], 0, 0, 0);
            }
            __syncthreads();
        }

        // fold this 256-col n-chunk of h into pv (h never materialized)
        #pragma unroll
        for (int ni = 0; ni < 4; ++ni) {
            const int col = n0 * 256 + wave * 64 + ni * 16 + l15;
            const float b1v = b1[col];
            const float w2v = W2[col];
            #pragma unroll
            for (int mi = 0; mi < 4; ++mi)
                #pragma unroll
                for (int r = 0; r < 4; ++r) {
                    const float h = fast_tanh(acc[mi][ni][r] + b1v);
                    pv[mi][r] = fmaf(h, w2v, pv[mi][r]);
                }
        }
    }

    // reduce pv over the 16 col-lanes (C/D layout: row = kgrp*4+r, col = l15)
    #pragma unroll
    for (int mi = 0; mi < 4; ++mi)
        #pragma unroll
        for (int r = 0; r < 4; ++r) {
            float s = pv[mi][r];
            s += __shfl_xor(s, 1);
            s += __shfl_xor(s, 2);
            s += __shfl_xor(s, 4);
            s += __shfl_xor(s, 8);
            if (l15 == 0) pv_part[wave][mi * 16 + kgrp * 4 + r] = s;
        }
    __syncthreads();
    if (tid < 64) {
        float s = b2[0];
        #pragma unroll
        for (int w = 0; w < 4; ++w) s += pv_part[w][tid];
        const float sg = 1.0f / (1.0f + __expf(-s));
        const float v = sg * mask[r0 + tid];
        val_ws[r0 + tid] = v;
        vrow[tid] = v;
    }
    __syncthreads();

    // unnormalized pooled partial for this block (normalization commutes)
    {
        const int kc = tid << 2;
        float a0 = 0.f, a1 = 0.f, a2 = 0.f, a3 = 0.f;
        for (int row = 0; row < 64; ++row) {
            const float v = vrow[row];
            const float4 xv = *reinterpret_cast<const float4*>(
                x + (size_t)(r0 + row) * D_ + kc);
            a0 = fmaf(xv.x, v, a0);
            a1 = fmaf(xv.y, v, a1);
            a2 = fmaf(xv.z, v, a2);
            a3 = fmaf(xv.w, v, a3);
        }
        *reinterpret_cast<float4*>(pooled_part + (size_t)blockIdx.x * D_ + kc) =
            make_float4(a0, a1, a2, a3);
    }

    // ---- inline finalize: last of the batch's 8 blocks does it ----
    __threadfence();                       // release our val/pooled writes
    __syncthreads();
    if (tid == 0) {
        const unsigned int old = atomicAdd(&cnt[bb], 1u);
        lastflag = (old == 7u) ? 1 : 0;
    }
    __syncthreads();
    if (!lastflag) return;
    __threadfence();                       // acquire the other 7 blocks' writes

    {
        float* sred = &pv_part[0][0];      // 256 floats, pv_part is dead
        const int b = bb;

        const float v0 = val_ws[b * J_ + tid];
        const float v1 = val_ws[b * J_ + 256 + tid];
        sred[tid] = v0 + v1;
        __syncthreads();
        for (int s = 128; s > 0; s >>= 1) {
            if (tid < s) sred[tid] += sred[tid + s];
            __syncthreads();
        }
        const float inv = 1.0f / sred[0];

        out[192 + b * J_ + tid]       = v0 * inv;
        out[192 + b * J_ + 256 + tid] = v1 * inv;

        const int k = tid << 2;
        float acc3[3] = {0.f, 0.f, 0.f};
        #pragma unroll
        for (int c = 0; c < 4; ++c) {
            float p = 0.f;
            #pragma unroll
            for (int i = 0; i < 8; ++i)
                p += pooled_part[(size_t)(b * 8 + i) * D_ + k + c];
            p *= inv;
            acc3[0] = fmaf(p, W3[(k + c) * 3 + 0], acc3[0]);
            acc3[1] = fmaf(p, W3[(k + c) * 3 + 1], acc3[1]);
            acc3[2] = fmaf(p, W3[(k + c) * 3 + 2], acc3[2]);
        }
        for (int o = 0; o < 3; ++o) {
            __syncthreads();
            sred[tid] = acc3[o];
            __syncthreads();
            for (int s = 128; s > 0; s >>= 1) {
                if (tid < s) sred[tid] += sred[tid + s];
                __syncthreads();
            }
            if (tid == 0) out[b * 3 + o] = sred[0] + b3[o];
        }
    }
}

extern "C" void kernel_launch(void* const* d_in, const int* in_sizes, int n_in,
                              void* d_out, int out_size, void* d_ws, size_t ws_size,
                              hipStream_t stream) {
    const float* x    = (const float*)d_in[0];
    const float* mask = (const float*)d_in[1];
    const float* W1   = (const float*)d_in[2];
    const float* b1   = (const float*)d_in[3];
    const float* W2   = (const float*)d_in[4];
    const float* b2   = (const float*)d_in[5];
    const float* W3   = (const float*)d_in[6];
    const float* b3   = (const float*)d_in[7];
    float* out = (float*)d_out;

    unsigned short* W1t = (unsigned short*)d_ws;                          // 2 MB
    float* val_ws       = (float*)((char*)d_ws + 2097152);                // 128 KB
    float* pooled_part  = (float*)((char*)d_ws + 2097152 + 131072);       // 2 MB
    unsigned int* cnt   = (unsigned int*)((char*)d_ws + 2097152 + 131072 + 2097152);

    transpose_cast_w1<<<dim3(16, 16), 256, 0, stream>>>(W1, W1t, cnt);
    gemm_score_kernel<<<512, 256, 0, stream>>>(x, W1t, b1, W2, b2, mask,
                                               W3, b3, out, val_ws, pooled_part, cnt);
}